// Round 6
// baseline (353.100 us; speedup 1.0000x reference)
//
#include <hip/hip_runtime.h>

// ---------------------------------------------------------------------------
// MultiHeadSelfAttention  B=4 L=2048 D=1024 H=16 hd=64, fp32 in/out.
//   prep:      x,W -> bf16; rope tables
//   gemm v3:   v1 shell (256 thr, 4 waves 2x2, BM=BN=128, same epilogues) +
//              counted-vmcnt ring ONLY: BK=32, ring-3 LDS (48KB total, the
//              proven footprint), stage 2 tiles ahead, vmcnt(4) per tile,
//              never vmcnt(0) in-loop. Loop shape == attn v10's (proven).
//              R4/R5: 144KB-LDS/512-thr variant killed the container twice;
//              reverted to in-envelope config, kept only the tested lever.
//   attn v10:  unchanged (R3-proven; issue-mix plateau ~135us).
//   gemm v3<1>: d_out = O @ Wo^T
// ---------------------------------------------------------------------------

typedef __bf16 bf16_t;
typedef __bf16 bf16x8 __attribute__((ext_vector_type(8)));
typedef __bf16 bf16x4 __attribute__((ext_vector_type(4)));
typedef float  floatx4 __attribute__((ext_vector_type(4)));
typedef unsigned int u32x2 __attribute__((ext_vector_type(2)));

#define B_  4
#define L_  2048
#define D_  1024
#define H_  16
#define HD_ 64
#define M_  (B_*L_)

__device__ __forceinline__ void async_copy16(const bf16_t* g, bf16_t* l) {
  __builtin_amdgcn_global_load_lds(
      (const __attribute__((address_space(1))) void*)g,
      (__attribute__((address_space(3))) void*)l, 16, 0, 0);
}

__device__ __forceinline__ unsigned int pack_bf16(float a, float b) {
  unsigned short ua = __builtin_bit_cast(unsigned short, (bf16_t)a);
  unsigned short ub = __builtin_bit_cast(unsigned short, (bf16_t)b);
  return (unsigned int)ua | ((unsigned int)ub << 16);
}

// ------------------------------ prep ---------------------------------------
__global__ void prep_kernel(const float* __restrict__ x,
                            const float* __restrict__ wq, const float* __restrict__ wk,
                            const float* __restrict__ wv, const float* __restrict__ wo,
                            bf16_t* __restrict__ xb,
                            bf16_t* __restrict__ wqb, bf16_t* __restrict__ wkb,
                            bf16_t* __restrict__ wvb, bf16_t* __restrict__ wob,
                            float* __restrict__ cosT, float* __restrict__ sinT)
{
  const int NX = M_*D_;
  const int NW = D_*D_;
  int i = blockIdx.x*256 + threadIdx.x;
  if (i < NX) { xb[i] = (bf16_t)x[i]; return; }
  i -= NX;
  if (i < NW) { wqb[i] = (bf16_t)wq[i]; return; }
  i -= NW;
  if (i < NW) { wkb[i] = (bf16_t)wk[i]; return; }
  i -= NW;
  if (i < NW) { wvb[i] = (bf16_t)wv[i]; return; }
  i -= NW;
  if (i < NW) { wob[i] = (bf16_t)wo[i]; return; }
  i -= NW;
  if (i < L_*32) {
    int l = i >> 5, f = i & 31;
    double inv = pow(10000.0, -(double)f / 32.0);
    double ang = (double)l * inv;
    cosT[i] = (float)cos(ang);
    sinT[i] = (float)sin(ang);
  }
}

// ------------------------------ GEMM v3 (C = A * W^T) ----------------------
// 256 threads, 4 waves (2Mx2N, 64x64/wave), BM=BN=128, BK=32.
// LDS ring-3: per buf A[128x32]=8KB + B[128x32]=8KB; 3 bufs = 48KB.
// K-tiles t=0..31, buf c=t%3. During tile t: stage tile t+2 into (t+2)%3
// (buffer computed at t-1 -> dead). 4 loads/tile/thread. Boundary vmcnt(4):
// tile t+1's 4 loads (issued at t-1, ~2 tile-times of cover) landed; t+2's
// 4 stay in flight. One barrier per tile; ds_reads of c complete before each
// wave's MFMA (compiler lgkm waits), hence before the barrier, hence before
// t+1's stages overwrite c. Tail: clamped re-stages into dead bufs keep the
// per-wave vmcnt FIFO count uniform; final vmcnt(0) drains before epilogue.
// 4-slot XOR swizzle on 64B rows -> 2-way read aliasing only (free, m136).
template<int MODE>
__global__ __launch_bounds__(256) void gemm_kernel(
    const bf16_t* __restrict__ A,
    const bf16_t* __restrict__ W0, const bf16_t* __restrict__ W1, const bf16_t* __restrict__ W2,
    bf16_t* __restrict__ C0, bf16_t* __restrict__ C1, bf16_t* __restrict__ C2,
    float* __restrict__ Cf,
    const float* __restrict__ cosT, const float* __restrict__ sinT)
{
  __shared__ __align__(16) bf16_t SA[3][128*32];   // 8KB x3
  __shared__ __align__(16) bf16_t SB[3][128*32];   // 8KB x3
  const int KD = 1024, ND = 1024;
  const int NT = 32;   // K-tiles of 32
  int z = (MODE==0) ? (int)blockIdx.z : 0;
  const bf16_t* W = (MODE==1) ? W0 : (z==0 ? W0 : (z==1 ? W1 : W2));
  int m0 = blockIdx.y*128, n0 = blockIdx.x*128;
  int tid = threadIdx.x;
  int wave = tid>>6, lane = tid&63, quad = lane>>4, lr = lane&15;
  int wm = wave>>1, wn = wave&1;
  int srow16 = lane>>2;               // row within a 16-row staged chunk
  int sslot4 = lane&3;                // 16B slot within a 64B row

  floatx4 zero4 = {0.f,0.f,0.f,0.f};
  floatx4 acc[4][4];
  #pragma unroll
  for (int i=0;i<4;i++)
    #pragma unroll
    for (int j=0;j<4;j++) acc[i][j] = zero4;

  // stage one 16-row chunk (64B/row); landing = base + lane*16B, so lane's
  // 16B slot (lane&3) fetches the XOR-swizzled source column.
  auto stageA = [&](int ts, int c, int j) {
    int row = j*64 + wave*16 + srow16;
    int col = ((sslot4 ^ (row&3)) << 3);
    async_copy16(A + (size_t)(m0+row)*KD + ts*32 + col, &SA[c][(j*64 + wave*16)*32]);
  };
  auto stageB = [&](int ts, int c, int j) {
    int row = j*64 + wave*16 + srow16;
    int col = ((sslot4 ^ (row&3)) << 3);
    async_copy16(W + (size_t)(n0+row)*KD + ts*32 + col, &SB[c][(j*64 + wave*16)*32]);
  };

  // prologue: tiles 0 and 1 in flight (8 loads); wait tile 0 only.
  stageA(0,0,0); stageA(0,0,1); stageB(0,0,0); stageB(0,0,1);
  stageA(1,1,0); stageA(1,1,1); stageB(1,1,0); stageB(1,1,1);
  asm volatile("s_waitcnt vmcnt(4)" ::: "memory");
  __builtin_amdgcn_s_barrier();

  #pragma unroll 1
  for (int t = 0; t < NT; ++t) {
    int c  = t % 3;
    int cn = (t+2) % 3;
    int ts = (t+2 < NT) ? (t+2) : (NT-1);   // tail clamp: dead-buf re-stage
    stageA(ts,cn,0); stageA(ts,cn,1); stageB(ts,cn,0); stageB(ts,cn,1);

    bf16x8 af[4], bfr[4];
    #pragma unroll
    for (int mi=0;mi<4;mi++)
      af[mi]  = *(const bf16x8*)&SA[c][(wm*64+mi*16+lr)*32 + ((quad^(lr&3))<<3)];
    #pragma unroll
    for (int ni=0;ni<4;ni++)
      bfr[ni] = *(const bf16x8*)&SB[c][(wn*64+ni*16+lr)*32 + ((quad^(lr&3))<<3)];
    #pragma unroll
    for (int mi=0;mi<4;mi++)
      #pragma unroll
      for (int ni=0;ni<4;ni++)
        acc[mi][ni] = __builtin_amdgcn_mfma_f32_16x16x32_bf16(af[mi], bfr[ni], acc[mi][ni], 0,0,0);

    // counted drain: tile t+1 landed; the 4 loads of tile t+2 may fly.
    asm volatile("s_waitcnt vmcnt(4)" ::: "memory");
    __builtin_amdgcn_s_barrier();
  }
  asm volatile("s_waitcnt vmcnt(0)" ::: "memory");  // drain tail re-stages

  if (MODE==1) {
    #pragma unroll
    for (int mi=0;mi<4;mi++) {
      int row = m0 + wm*64 + mi*16 + quad*4;
      #pragma unroll
      for (int ni=0;ni<4;ni++) {
        int col = n0 + wn*64 + ni*16 + lr;
        #pragma unroll
        for (int r=0;r<4;r++)
          Cf[(size_t)(row+r)*ND + col] = acc[mi][ni][r];
      }
    }
  } else if (z < 2) {
    bf16_t* Cb = (z==0) ? C0 : C1;
    const float sc = (z==0) ? 0.18033688011112042f : 1.0f;  // 0.125*log2(e)
    #pragma unroll
    for (int mi=0;mi<4;mi++) {
      int row = m0 + wm*64 + mi*16 + quad*4;
      int l = row & 2047;
      #pragma unroll
      for (int ni=0;ni<2;ni++) {
        int col = n0 + wn*64 + ni*16 + lr;
        int f = ni*16 + lr;
        #pragma unroll
        for (int r=0;r<4;r++) {
          float c = cosT[(l+r)*32 + f];
          float s = sinT[(l+r)*32 + f];
          float lo = acc[mi][ni][r], hi = acc[mi][ni+2][r];
          Cb[(size_t)(row+r)*ND + col]      = (bf16_t)((lo*c - hi*s)*sc);
          Cb[(size_t)(row+r)*ND + col + 32] = (bf16_t)((hi*c + lo*s)*sc);
        }
      }
    }
  } else {
    #pragma unroll
    for (int mi=0;mi<4;mi++) {
      int row0 = m0 + wm*64 + mi*16 + quad*4;
      int bb = row0 >> 11, ll = row0 & 2047;
      #pragma unroll
      for (int ni=0;ni<4;ni++) {
        int col = n0 + wn*64 + ni*16 + lr;
        int hh = col >> 6, dd = col & 63;
        uint2 val;
        val.x = pack_bf16(acc[mi][ni][0], acc[mi][ni][1]);
        val.y = pack_bf16(acc[mi][ni][2], acc[mi][ni][3]);
        *(uint2*)&C2[((size_t)((bb<<4)+hh)*64 + dd)*2048 + ll] = val;
      }
    }
  }
}

// ------------------------------ flash attention v10 ------------------------
// grid (64,16): x=bh (XCD-local), y=q128. KVBLK=64, ring-3 (48KB), 2-deep
// prefetch, counted vmcnt(4). At its issue-mix plateau (~70% VALU+MFMA busy).
__global__ __launch_bounds__(256) void attn_kernel(
    const bf16_t* __restrict__ Q, const bf16_t* __restrict__ K,
    const bf16_t* __restrict__ Vt, bf16_t* __restrict__ O)
{
  __shared__ __align__(16) bf16_t Ks[3][4096];   // 64kv x 64d  (8KB x3)
  __shared__ __align__(16) bf16_t Vs[3][4096];   // 64d  x 64kv (8KB x3)
  int tid = threadIdx.x;
  int wave = tid>>6, lane = tid&63, quad = lane>>4, lr = lane&15;
  int bh = blockIdx.x; int b = bh>>4, h = bh&15;
  int q0 = blockIdx.y*128 + wave*32;
  size_t rowQ = (size_t)b*L_ + q0;

  int slr = (lr&3) | ((lr&4)<<1) | ((lr&8)>>1);
  int srow8 = lane>>3;
  int sslot = lane&7;

  bf16x8 qf[2][2];
  #pragma unroll
  for (int n=0;n<2;n++)
    #pragma unroll
    for (int ks=0;ks<2;ks++)
      qf[n][ks] = *(const bf16x8*)&Q[(rowQ + n*16 + lr)*D_ + h*HD_ + ks*32 + quad*8];

  const bf16_t* Kg = K + (size_t)b*L_*D_ + h*HD_;
  const bf16_t* Vg = Vt + (size_t)bh*HD_*L_;

  bf16x8 onesf;
  #pragma unroll
  for (int j=0;j<8;j++) onesf[j] = (bf16_t)1.0f;

  floatx4 zero4 = {0.f,0.f,0.f,0.f};
  floatx4 accO[2][4];
  floatx4 accS[2];
  accS[0] = zero4; accS[1] = zero4;
  #pragma unroll
  for (int n=0;n<2;n++)
    #pragma unroll
    for (int dt=0;dt<4;dt++) accO[n][dt] = zero4;

  auto stage = [&](int it, int c) {
    #pragma unroll
    for (int j=0;j<2;j++) {
      int row = wave*16 + j*8 + srow8;
      int col = ((sslot ^ (row&7)) << 3);
      async_copy16(Kg + (size_t)(it*64 + row)*D_ + col, &Ks[c][(wave*16 + j*8)*64]);
      async_copy16(Vg + (size_t)row*L_ + it*64 + col,   &Vs[c][(wave*16 + j*8)*64]);
    }
  };

  stage(0, 0);
  stage(1, 1);
  asm volatile("s_waitcnt vmcnt(4)" ::: "memory");
  __builtin_amdgcn_s_barrier();

  #pragma unroll 1
  for (int it = 0; it < 32; ++it) {
    int c = it % 3;
    if (it < 30) stage(it+2, (it+2) % 3);

    floatx4 St[2][4];
    #pragma unroll
    for (int t=0;t<4;t++) { St[0][t]=zero4; St[1][t]=zero4; }
    #pragma unroll
    for (int t=0;t<4;t++) {
      #pragma unroll
      for (int ks=0;ks<2;ks++) {
        bf16x8 kf = *(const bf16x8*)&Ks[c][(t*16+slr)*64 + (((ks*4+quad) ^ (slr&7))<<3)];
        St[0][t] = __builtin_amdgcn_mfma_f32_16x16x32_bf16(kf, qf[0][ks], St[0][t], 0,0,0);
        St[1][t] = __builtin_amdgcn_mfma_f32_16x16x32_bf16(kf, qf[1][ks], St[1][t], 0,0,0);
      }
    }

    bf16x8 pfv[2][2];
    #pragma unroll
    for (int n=0;n<2;n++) {
      #pragma unroll
      for (int hh=0;hh<2;hh++) {
        unsigned int w00 = pack_bf16(exp2f(St[n][2*hh][0]),   exp2f(St[n][2*hh][1]));
        unsigned int w01 = pack_bf16(exp2f(St[n][2*hh][2]),   exp2f(St[n][2*hh][3]));
        unsigned int w10 = pack_bf16(exp2f(St[n][2*hh+1][0]), exp2f(St[n][2*hh+1][1]));
        unsigned int w11 = pack_bf16(exp2f(St[n][2*hh+1][2]), exp2f(St[n][2*hh+1][3]));
        u32x2 r0 = __builtin_amdgcn_permlane32_swap(w00, w10, false, false);
        u32x2 r1 = __builtin_amdgcn_permlane32_swap(w01, w11, false, false);
        union { unsigned int u[4]; bf16x8 v; } pu;
        pu.u[0] = r0.x; pu.u[1] = r1.x; pu.u[2] = r0.y; pu.u[3] = r1.y;
        pfv[n][hh] = pu.v;
      }
    }

    #pragma unroll
    for (int dt=0;dt<4;dt++) {
      #pragma unroll
      for (int hh=0;hh<2;hh++) {
        bf16x8 vf = *(const bf16x8*)&Vs[c][(dt*16+lr)*64 + (((hh*4+quad) ^ (lr&7))<<3)];
        accO[0][dt] = __builtin_amdgcn_mfma_f32_16x16x32_bf16(vf, pfv[0][hh], accO[0][dt], 0,0,0);
        accO[1][dt] = __builtin_amdgcn_mfma_f32_16x16x32_bf16(vf, pfv[1][hh], accO[1][dt], 0,0,0);
      }
    }
    accS[0] = __builtin_amdgcn_mfma_f32_16x16x32_bf16(onesf, pfv[0][0], accS[0], 0,0,0);
    accS[1] = __builtin_amdgcn_mfma_f32_16x16x32_bf16(onesf, pfv[1][0], accS[1], 0,0,0);
    accS[0] = __builtin_amdgcn_mfma_f32_16x16x32_bf16(onesf, pfv[0][1], accS[0], 0,0,0);
    accS[1] = __builtin_amdgcn_mfma_f32_16x16x32_bf16(onesf, pfv[1][1], accS[1], 0,0,0);

    if (it < 30) {
      asm volatile("s_waitcnt vmcnt(4)" ::: "memory");
    } else {
      asm volatile("s_waitcnt vmcnt(0)" ::: "memory");
    }
    __builtin_amdgcn_s_barrier();
  }

  float inv0 = 1.0f / accS[0][0];
  float inv1 = 1.0f / accS[1][0];
  #pragma unroll
  for (int n=0;n<2;n++) {
    float inv = n ? inv1 : inv0;
    #pragma unroll
    for (int dt=0;dt<4;dt++) {
      uint2 w;
      w.x = pack_bf16(accO[n][dt][0]*inv, accO[n][dt][1]*inv);
      w.y = pack_bf16(accO[n][dt][2]*inv, accO[n][dt][3]*inv);
      *(uint2*)&O[(rowQ + n*16 + lr)*D_ + h*HD_ + dt*16 + quad*4] = w;
    }
  }
}

// ------------------------------ launch -------------------------------------
extern "C" void kernel_launch(void* const* d_in, const int* in_sizes, int n_in,
                              void* d_out, int out_size, void* d_ws, size_t ws_size,
                              hipStream_t stream) {
  const float* x  = (const float*)d_in[0];
  const float* wq = (const float*)d_in[1];
  const float* wk = (const float*)d_in[2];
  const float* wv = (const float*)d_in[3];
  const float* wo = (const float*)d_in[4];

  char* ws = (char*)d_ws;
  bf16_t* xb  = (bf16_t*)(ws);                       // 16MB; reused as O after attn
  bf16_t* Qb  = (bf16_t*)(ws + (size_t)(16u<<20));
  bf16_t* Kb  = (bf16_t*)(ws + (size_t)(32u<<20));
  bf16_t* Vtb = (bf16_t*)(ws + (size_t)(48u<<20));
  bf16_t* wqb = (bf16_t*)(ws + (size_t)(64u<<20));
  bf16_t* wkb = (bf16_t*)(ws + (size_t)(66u<<20));
  bf16_t* wvb = (bf16_t*)(ws + (size_t)(68u<<20));
  bf16_t* wob = (bf16_t*)(ws + (size_t)(70u<<20));
  float* cosT = (float*)(ws + (size_t)(72u<<20));
  float* sinT = (float*)(ws + (size_t)(72u<<20) + (256u<<10));
  bf16_t* Ob = xb;

  prep_kernel<<<49408, 256, 0, stream>>>(x, wq, wk, wv, wo, xb, wqb, wkb, wvb, wob, cosT, sinT);
  gemm_kernel<0><<<dim3(8,64,3), 256, 0, stream>>>(xb, wqb, wkb, wvb, Qb, Kb, Vtb, nullptr, cosT, sinT);
  attn_kernel<<<dim3(64,16), 256, 0, stream>>>(Qb, Kb, Vtb, Ob);
  gemm_kernel<1><<<dim3(8,64,1), 256, 0, stream>>>(Ob, wob, nullptr, nullptr,
                                                   nullptr, nullptr, nullptr, (float*)d_out, cosT, sinT);
}

// Round 7
// 316.711 us; speedup vs baseline: 1.1149x; 1.1149x over previous
//
#include <hip/hip_runtime.h>

// ---------------------------------------------------------------------------
// MultiHeadSelfAttention  B=4 L=2048 D=1024 H=16 hd=64, fp32 in/out.
//   prep:      x,W -> bf16; rope tables
//   gemm v1:   (restored R3 form; v3's BK=32 ring REGRESSED ~28us: occupancy
//              5->3 blocks/CU beats counted-vmcnt ILP, per m114) 128x128 BK=64
//              2-phase, 32KB LDS, grid (8,64,3)/(8,64).
//   attn v11:  = v10 structure + instruction diet. Theory: VALUBusy 70% +
//              MfmaUtil 24% = 94% issue-occupancy, invariant across v7-v10
//              -> attn is SIMD-issue-bound; all three structural nulls are
//              explained (they removed pipe work/stalls, not instructions).
//              (a) kv-loop unrolled x3 -> ring index compile-time -> all 16
//              ds_read addrs fold to hoisted base + offset: imm.
//              (b) v_cvt_pk_bf16_f32 inline asm replaces 5-op packs (T12).
//   gemm v1<1>: d_out = O @ Wo^T
// ---------------------------------------------------------------------------

typedef __bf16 bf16_t;
typedef __bf16 bf16x8 __attribute__((ext_vector_type(8)));
typedef __bf16 bf16x4 __attribute__((ext_vector_type(4)));
typedef float  floatx4 __attribute__((ext_vector_type(4)));
typedef unsigned int u32x2 __attribute__((ext_vector_type(2)));

#define B_  4
#define L_  2048
#define D_  1024
#define H_  16
#define HD_ 64
#define M_  (B_*L_)

__device__ __forceinline__ void async_copy16(const bf16_t* g, bf16_t* l) {
  __builtin_amdgcn_global_load_lds(
      (const __attribute__((address_space(1))) void*)g,
      (__attribute__((address_space(3))) void*)l, 16, 0, 0);
}

__device__ __forceinline__ unsigned int pack_bf16(float a, float b) {
  unsigned short ua = __builtin_bit_cast(unsigned short, (bf16_t)a);
  unsigned short ub = __builtin_bit_cast(unsigned short, (bf16_t)b);
  return (unsigned int)ua | ((unsigned int)ub << 16);
}

// single-instruction packed f32x2 -> bf16x2 (RTNE), no gfx950 builtin (m240)
__device__ __forceinline__ unsigned int cvt_pk(float lo, float hi) {
  unsigned int r;
  asm("v_cvt_pk_bf16_f32 %0, %1, %2" : "=v"(r) : "v"(lo), "v"(hi));
  return r;
}

// ------------------------------ prep ---------------------------------------
__global__ void prep_kernel(const float* __restrict__ x,
                            const float* __restrict__ wq, const float* __restrict__ wk,
                            const float* __restrict__ wv, const float* __restrict__ wo,
                            bf16_t* __restrict__ xb,
                            bf16_t* __restrict__ wqb, bf16_t* __restrict__ wkb,
                            bf16_t* __restrict__ wvb, bf16_t* __restrict__ wob,
                            float* __restrict__ cosT, float* __restrict__ sinT)
{
  const int NX = M_*D_;
  const int NW = D_*D_;
  int i = blockIdx.x*256 + threadIdx.x;
  if (i < NX) { xb[i] = (bf16_t)x[i]; return; }
  i -= NX;
  if (i < NW) { wqb[i] = (bf16_t)wq[i]; return; }
  i -= NW;
  if (i < NW) { wkb[i] = (bf16_t)wk[i]; return; }
  i -= NW;
  if (i < NW) { wvb[i] = (bf16_t)wv[i]; return; }
  i -= NW;
  if (i < NW) { wob[i] = (bf16_t)wo[i]; return; }
  i -= NW;
  if (i < L_*32) {
    int l = i >> 5, f = i & 31;
    double inv = pow(10000.0, -(double)f / 32.0);
    double ang = (double)l * inv;
    cosT[i] = (float)cos(ang);
    sinT[i] = (float)sin(ang);
  }
}

// ------------------------------ GEMM v1 (C = A * W^T) ----------------------
template<int MODE>
__global__ __launch_bounds__(256) void gemm_kernel(
    const bf16_t* __restrict__ A,
    const bf16_t* __restrict__ W0, const bf16_t* __restrict__ W1, const bf16_t* __restrict__ W2,
    bf16_t* __restrict__ C0, bf16_t* __restrict__ C1, bf16_t* __restrict__ C2,
    float* __restrict__ Cf,
    const float* __restrict__ cosT, const float* __restrict__ sinT)
{
  __shared__ __align__(16) bf16_t As[128*64];
  __shared__ __align__(16) bf16_t Bs[128*64];
  const int KD = 1024, ND = 1024;
  int z = (MODE==0) ? (int)blockIdx.z : 0;
  const bf16_t* W = (MODE==1) ? W0 : (z==0 ? W0 : (z==1 ? W1 : W2));
  int m0 = blockIdx.y*128, n0 = blockIdx.x*128;
  int tid = threadIdx.x;
  int wave = tid>>6, lane = tid&63, quad = lane>>4, lr = lane&15;
  int wm = wave>>1, wn = wave&1;
  int srow = lane>>3, sslot = lane&7;

  floatx4 zero4 = {0.f,0.f,0.f,0.f};
  floatx4 acc[4][4];
  #pragma unroll
  for (int i=0;i<4;i++)
    #pragma unroll
    for (int j=0;j<4;j++) acc[i][j] = zero4;

  #pragma unroll 1
  for (int k0 = 0; k0 < KD; k0 += 64) {
    #pragma unroll
    for (int j=0;j<4;j++) {
      int chunk = wave + j*4;
      int row = chunk*8 + srow;
      int col = ((sslot ^ (row&7)) << 3);
      async_copy16(A + (size_t)(m0+row)*KD + k0 + col, &As[chunk*512]);
      async_copy16(W + (size_t)(n0+row)*KD + k0 + col, &Bs[chunk*512]);
    }
    __syncthreads();
    #pragma unroll
    for (int ks=0; ks<2; ks++) {
      bf16x8 af[4], bfr[4];
      #pragma unroll
      for (int mi=0;mi<4;mi++)
        af[mi] = *(const bf16x8*)&As[(wm*64+mi*16+lr)*64 + (((ks*4+quad) ^ (lr&7))<<3)];
      #pragma unroll
      for (int ni=0;ni<4;ni++)
        bfr[ni] = *(const bf16x8*)&Bs[(wn*64+ni*16+lr)*64 + (((ks*4+quad) ^ (lr&7))<<3)];
      #pragma unroll
      for (int mi=0;mi<4;mi++)
        #pragma unroll
        for (int ni=0;ni<4;ni++)
          acc[mi][ni] = __builtin_amdgcn_mfma_f32_16x16x32_bf16(af[mi], bfr[ni], acc[mi][ni], 0,0,0);
    }
    __syncthreads();
  }

  if (MODE==1) {
    #pragma unroll
    for (int mi=0;mi<4;mi++) {
      int row = m0 + wm*64 + mi*16 + quad*4;
      #pragma unroll
      for (int ni=0;ni<4;ni++) {
        int col = n0 + wn*64 + ni*16 + lr;
        #pragma unroll
        for (int r=0;r<4;r++)
          Cf[(size_t)(row+r)*ND + col] = acc[mi][ni][r];
      }
    }
  } else if (z < 2) {
    bf16_t* Cb = (z==0) ? C0 : C1;
    const float sc = (z==0) ? 0.18033688011112042f : 1.0f;  // 0.125*log2(e)
    #pragma unroll
    for (int mi=0;mi<4;mi++) {
      int row = m0 + wm*64 + mi*16 + quad*4;
      int l = row & 2047;
      #pragma unroll
      for (int ni=0;ni<2;ni++) {
        int col = n0 + wn*64 + ni*16 + lr;
        int f = ni*16 + lr;
        #pragma unroll
        for (int r=0;r<4;r++) {
          float c = cosT[(l+r)*32 + f];
          float s = sinT[(l+r)*32 + f];
          float lo = acc[mi][ni][r], hi = acc[mi][ni+2][r];
          Cb[(size_t)(row+r)*ND + col]      = (bf16_t)((lo*c - hi*s)*sc);
          Cb[(size_t)(row+r)*ND + col + 32] = (bf16_t)((hi*c + lo*s)*sc);
        }
      }
    }
  } else {
    #pragma unroll
    for (int mi=0;mi<4;mi++) {
      int row0 = m0 + wm*64 + mi*16 + quad*4;
      int bb = row0 >> 11, ll = row0 & 2047;
      #pragma unroll
      for (int ni=0;ni<4;ni++) {
        int col = n0 + wn*64 + ni*16 + lr;
        int hh = col >> 6, dd = col & 63;
        uint2 val;
        val.x = pack_bf16(acc[mi][ni][0], acc[mi][ni][1]);
        val.y = pack_bf16(acc[mi][ni][2], acc[mi][ni][3]);
        *(uint2*)&C2[((size_t)((bb<<4)+hh)*64 + dd)*2048 + ll] = val;
      }
    }
  }
}

// ------------------------------ flash attention v11 ------------------------
// grid (64,16): x=bh (XCD-local), y=q128. KVBLK=64, ring-3 (48KB), 2-deep
// prefetch, counted vmcnt(4). v11: kv-loop unrolled x3 so the ring index is
// compile-time (LDS addrs fold to base+offset imm); cvt_pk inline asm.
__global__ __launch_bounds__(256) void attn_kernel(
    const bf16_t* __restrict__ Q, const bf16_t* __restrict__ K,
    const bf16_t* __restrict__ Vt, bf16_t* __restrict__ O)
{
  __shared__ __align__(16) bf16_t Ks[3][4096];   // 64kv x 64d  (8KB x3)
  __shared__ __align__(16) bf16_t Vs[3][4096];   // 64d  x 64kv (8KB x3)
  int tid = threadIdx.x;
  int wave = tid>>6, lane = tid&63, quad = lane>>4, lr = lane&15;
  int bh = blockIdx.x; int b = bh>>4, h = bh&15;
  int q0 = blockIdx.y*128 + wave*32;
  size_t rowQ = (size_t)b*L_ + q0;

  int slr = (lr&3) | ((lr&4)<<1) | ((lr&8)>>1);
  int srow8 = lane>>3;
  int sslot = lane&7;

  bf16x8 qf[2][2];
  #pragma unroll
  for (int n=0;n<2;n++)
    #pragma unroll
    for (int ks=0;ks<2;ks++)
      qf[n][ks] = *(const bf16x8*)&Q[(rowQ + n*16 + lr)*D_ + h*HD_ + ks*32 + quad*8];

  const bf16_t* Kg = K + (size_t)b*L_*D_ + h*HD_;
  const bf16_t* Vg = Vt + (size_t)bh*HD_*L_;

  bf16x8 onesf;
  #pragma unroll
  for (int j=0;j<8;j++) onesf[j] = (bf16_t)1.0f;

  floatx4 zero4 = {0.f,0.f,0.f,0.f};
  floatx4 accO[2][4];
  floatx4 accS[2];
  accS[0] = zero4; accS[1] = zero4;
  #pragma unroll
  for (int n=0;n<2;n++)
    #pragma unroll
    for (int dt=0;dt<4;dt++) accO[n][dt] = zero4;

  auto stage = [&](int it, int c) {
    #pragma unroll
    for (int j=0;j<2;j++) {
      int row = wave*16 + j*8 + srow8;
      int col = ((sslot ^ (row&7)) << 3);
      async_copy16(Kg + (size_t)(it*64 + row)*D_ + col, &Ks[c][(wave*16 + j*8)*64]);
      async_copy16(Vg + (size_t)row*L_ + it*64 + col,   &Vs[c][(wave*16 + j*8)*64]);
    }
  };

  stage(0, 0);
  stage(1, 1);
  asm volatile("s_waitcnt vmcnt(4)" ::: "memory");
  __builtin_amdgcn_s_barrier();

// One kv-iteration. CC and DO_STAGE are compile-time -> LDS ring bases fold
// into ds_read offset immediates; stage target (CC+2)%3 folds too.
#define ATTN_BODY(IT, CC, DO_STAGE)                                           \
  {                                                                           \
    if (DO_STAGE) stage((IT)+2, ((CC)+2)%3);                                  \
    floatx4 St[2][4];                                                         \
    _Pragma("unroll")                                                         \
    for (int t=0;t<4;t++) { St[0][t]=zero4; St[1][t]=zero4; }                 \
    _Pragma("unroll")                                                         \
    for (int t=0;t<4;t++) {                                                   \
      _Pragma("unroll")                                                       \
      for (int ks=0;ks<2;ks++) {                                              \
        bf16x8 kf = *(const bf16x8*)&Ks[CC][(t*16+slr)*64 + (((ks*4+quad) ^ (slr&7))<<3)]; \
        St[0][t] = __builtin_amdgcn_mfma_f32_16x16x32_bf16(kf, qf[0][ks], St[0][t], 0,0,0); \
        St[1][t] = __builtin_amdgcn_mfma_f32_16x16x32_bf16(kf, qf[1][ks], St[1][t], 0,0,0); \
      }                                                                       \
    }                                                                         \
    bf16x8 pfv[2][2];                                                         \
    _Pragma("unroll")                                                         \
    for (int n=0;n<2;n++) {                                                   \
      _Pragma("unroll")                                                       \
      for (int hh=0;hh<2;hh++) {                                              \
        unsigned int w00 = cvt_pk(exp2f(St[n][2*hh][0]),   exp2f(St[n][2*hh][1]));   \
        unsigned int w01 = cvt_pk(exp2f(St[n][2*hh][2]),   exp2f(St[n][2*hh][3]));   \
        unsigned int w10 = cvt_pk(exp2f(St[n][2*hh+1][0]), exp2f(St[n][2*hh+1][1])); \
        unsigned int w11 = cvt_pk(exp2f(St[n][2*hh+1][2]), exp2f(St[n][2*hh+1][3])); \
        u32x2 r0 = __builtin_amdgcn_permlane32_swap(w00, w10, false, false);  \
        u32x2 r1 = __builtin_amdgcn_permlane32_swap(w01, w11, false, false);  \
        union { unsigned int u[4]; bf16x8 v; } pu;                            \
        pu.u[0] = r0.x; pu.u[1] = r1.x; pu.u[2] = r0.y; pu.u[3] = r1.y;       \
        pfv[n][hh] = pu.v;                                                    \
      }                                                                       \
    }                                                                         \
    _Pragma("unroll")                                                         \
    for (int dt=0;dt<4;dt++) {                                                \
      _Pragma("unroll")                                                       \
      for (int hh=0;hh<2;hh++) {                                              \
        bf16x8 vf = *(const bf16x8*)&Vs[CC][(dt*16+lr)*64 + (((hh*4+quad) ^ (lr&7))<<3)]; \
        accO[0][dt] = __builtin_amdgcn_mfma_f32_16x16x32_bf16(vf, pfv[0][hh], accO[0][dt], 0,0,0); \
        accO[1][dt] = __builtin_amdgcn_mfma_f32_16x16x32_bf16(vf, pfv[1][hh], accO[1][dt], 0,0,0); \
      }                                                                       \
    }                                                                         \
    accS[0] = __builtin_amdgcn_mfma_f32_16x16x32_bf16(onesf, pfv[0][0], accS[0], 0,0,0); \
    accS[1] = __builtin_amdgcn_mfma_f32_16x16x32_bf16(onesf, pfv[1][0], accS[1], 0,0,0); \
    accS[0] = __builtin_amdgcn_mfma_f32_16x16x32_bf16(onesf, pfv[0][1], accS[0], 0,0,0); \
    accS[1] = __builtin_amdgcn_mfma_f32_16x16x32_bf16(onesf, pfv[1][1], accS[1], 0,0,0); \
    if (DO_STAGE) { asm volatile("s_waitcnt vmcnt(4)" ::: "memory"); }        \
    else          { asm volatile("s_waitcnt vmcnt(0)" ::: "memory"); }        \
    __builtin_amdgcn_s_barrier();                                             \
  }

  #pragma unroll 1
  for (int itb = 0; itb < 30; itb += 3) {
    ATTN_BODY(itb+0, 0, true);
    ATTN_BODY(itb+1, 1, true);
    ATTN_BODY(itb+2, 2, true);
  }
  ATTN_BODY(30, 0, false);
  ATTN_BODY(31, 1, false);
#undef ATTN_BODY

  float inv0 = 1.0f / accS[0][0];
  float inv1 = 1.0f / accS[1][0];
  #pragma unroll
  for (int n=0;n<2;n++) {
    float inv = n ? inv1 : inv0;
    #pragma unroll
    for (int dt=0;dt<4;dt++) {
      uint2 w;
      w.x = cvt_pk(accO[n][dt][0]*inv, accO[n][dt][1]*inv);
      w.y = cvt_pk(accO[n][dt][2]*inv, accO[n][dt][3]*inv);
      *(uint2*)&O[(rowQ + n*16 + lr)*D_ + h*HD_ + dt*16 + quad*4] = w;
    }
  }
}

// ------------------------------ launch -------------------------------------
extern "C" void kernel_launch(void* const* d_in, const int* in_sizes, int n_in,
                              void* d_out, int out_size, void* d_ws, size_t ws_size,
                              hipStream_t stream) {
  const float* x  = (const float*)d_in[0];
  const float* wq = (const float*)d_in[1];
  const float* wk = (const float*)d_in[2];
  const float* wv = (const float*)d_in[3];
  const float* wo = (const float*)d_in[4];

  char* ws = (char*)d_ws;
  bf16_t* xb  = (bf16_t*)(ws);                       // 16MB; reused as O after attn
  bf16_t* Qb  = (bf16_t*)(ws + (size_t)(16u<<20));
  bf16_t* Kb  = (bf16_t*)(ws + (size_t)(32u<<20));
  bf16_t* Vtb = (bf16_t*)(ws + (size_t)(48u<<20));
  bf16_t* wqb = (bf16_t*)(ws + (size_t)(64u<<20));
  bf16_t* wkb = (bf16_t*)(ws + (size_t)(66u<<20));
  bf16_t* wvb = (bf16_t*)(ws + (size_t)(68u<<20));
  bf16_t* wob = (bf16_t*)(ws + (size_t)(70u<<20));
  float* cosT = (float*)(ws + (size_t)(72u<<20));
  float* sinT = (float*)(ws + (size_t)(72u<<20) + (256u<<10));
  bf16_t* Ob = xb;

  prep_kernel<<<49408, 256, 0, stream>>>(x, wq, wk, wv, wo, xb, wqb, wkb, wvb, wob, cosT, sinT);
  gemm_kernel<0><<<dim3(8,64,3), 256, 0, stream>>>(xb, wqb, wkb, wvb, Qb, Kb, Vtb, nullptr, cosT, sinT);
  attn_kernel<<<dim3(64,16), 256, 0, stream>>>(Qb, Kb, Vtb, Ob);
  gemm_kernel<1><<<dim3(8,64,1), 256, 0, stream>>>(Ob, wob, nullptr, nullptr,
                                                   nullptr, nullptr, nullptr, (float*)d_out, cosT, sinT);
}

// Round 8
// 313.031 us; speedup vs baseline: 1.1280x; 1.0118x over previous
//
#include <hip/hip_runtime.h>

// ---------------------------------------------------------------------------
// MultiHeadSelfAttention  B=4 L=2048 D=1024 H=16 hd=64, fp32 in/out.
//   prep:      x,W -> bf16; rope tables
//   gemm v1.1: v1 (128x128 BK=64 2-phase, 32KB LDS) + z=2 epilogue rerouted:
//              acc -> LDS (XOR-swizzled transpose, reusing the dead As/Bs
//              32KB) -> coalesced 16B/lane Vt stores. Old path: 16x 8B stores
//              at 4KB stride/lane = ~4-8x write amplification on 16MB.
//   attn v11:  FROZEN (R7 win matched prediction: issue-diet 134.6->124.1us).
//   gemm v1<1>: d_out = O @ Wo^T (unchanged)
// History: R6 ring/BK32 regressed (occupancy > ILP, m114); R4/R5 512thr/144KB
// killed the container; R7 diet +8% (issue-bound confirmed).
// ---------------------------------------------------------------------------

typedef __bf16 bf16_t;
typedef __bf16 bf16x8 __attribute__((ext_vector_type(8)));
typedef __bf16 bf16x4 __attribute__((ext_vector_type(4)));
typedef float  floatx4 __attribute__((ext_vector_type(4)));
typedef unsigned int u32x2 __attribute__((ext_vector_type(2)));

#define B_  4
#define L_  2048
#define D_  1024
#define H_  16
#define HD_ 64
#define M_  (B_*L_)

__device__ __forceinline__ void async_copy16(const bf16_t* g, bf16_t* l) {
  __builtin_amdgcn_global_load_lds(
      (const __attribute__((address_space(1))) void*)g,
      (__attribute__((address_space(3))) void*)l, 16, 0, 0);
}

__device__ __forceinline__ unsigned int pack_bf16(float a, float b) {
  unsigned short ua = __builtin_bit_cast(unsigned short, (bf16_t)a);
  unsigned short ub = __builtin_bit_cast(unsigned short, (bf16_t)b);
  return (unsigned int)ua | ((unsigned int)ub << 16);
}

// single-instruction packed f32x2 -> bf16x2 (RTNE), no gfx950 builtin (m240)
__device__ __forceinline__ unsigned int cvt_pk(float lo, float hi) {
  unsigned int r;
  asm("v_cvt_pk_bf16_f32 %0, %1, %2" : "=v"(r) : "v"(lo), "v"(hi));
  return r;
}

// ------------------------------ prep ---------------------------------------
__global__ void prep_kernel(const float* __restrict__ x,
                            const float* __restrict__ wq, const float* __restrict__ wk,
                            const float* __restrict__ wv, const float* __restrict__ wo,
                            bf16_t* __restrict__ xb,
                            bf16_t* __restrict__ wqb, bf16_t* __restrict__ wkb,
                            bf16_t* __restrict__ wvb, bf16_t* __restrict__ wob,
                            float* __restrict__ cosT, float* __restrict__ sinT)
{
  const int NX = M_*D_;
  const int NW = D_*D_;
  int i = blockIdx.x*256 + threadIdx.x;
  if (i < NX) { xb[i] = (bf16_t)x[i]; return; }
  i -= NX;
  if (i < NW) { wqb[i] = (bf16_t)wq[i]; return; }
  i -= NW;
  if (i < NW) { wkb[i] = (bf16_t)wk[i]; return; }
  i -= NW;
  if (i < NW) { wvb[i] = (bf16_t)wv[i]; return; }
  i -= NW;
  if (i < NW) { wob[i] = (bf16_t)wo[i]; return; }
  i -= NW;
  if (i < L_*32) {
    int l = i >> 5, f = i & 31;
    double inv = pow(10000.0, -(double)f / 32.0);
    double ang = (double)l * inv;
    cosT[i] = (float)cos(ang);
    sinT[i] = (float)sin(ang);
  }
}

// ------------------------------ GEMM v1.1 (C = A * W^T) --------------------
template<int MODE>
__global__ __launch_bounds__(256) void gemm_kernel(
    const bf16_t* __restrict__ A,
    const bf16_t* __restrict__ W0, const bf16_t* __restrict__ W1, const bf16_t* __restrict__ W2,
    bf16_t* __restrict__ C0, bf16_t* __restrict__ C1, bf16_t* __restrict__ C2,
    float* __restrict__ Cf,
    const float* __restrict__ cosT, const float* __restrict__ sinT)
{
  __shared__ __align__(16) bf16_t Sh[16384];   // As = Sh[0:8192), Bs = Sh[8192:)
  bf16_t* As = Sh;
  bf16_t* Bs = Sh + 8192;
  const int KD = 1024, ND = 1024;
  int z = (MODE==0) ? (int)blockIdx.z : 0;
  const bf16_t* W = (MODE==1) ? W0 : (z==0 ? W0 : (z==1 ? W1 : W2));
  int m0 = blockIdx.y*128, n0 = blockIdx.x*128;
  int tid = threadIdx.x;
  int wave = tid>>6, lane = tid&63, quad = lane>>4, lr = lane&15;
  int wm = wave>>1, wn = wave&1;
  int srow = lane>>3, sslot = lane&7;

  floatx4 zero4 = {0.f,0.f,0.f,0.f};
  floatx4 acc[4][4];
  #pragma unroll
  for (int i=0;i<4;i++)
    #pragma unroll
    for (int j=0;j<4;j++) acc[i][j] = zero4;

  #pragma unroll 1
  for (int k0 = 0; k0 < KD; k0 += 64) {
    #pragma unroll
    for (int j=0;j<4;j++) {
      int chunk = wave + j*4;
      int row = chunk*8 + srow;
      int col = ((sslot ^ (row&7)) << 3);
      async_copy16(A + (size_t)(m0+row)*KD + k0 + col, &As[chunk*512]);
      async_copy16(W + (size_t)(n0+row)*KD + k0 + col, &Bs[chunk*512]);
    }
    __syncthreads();
    #pragma unroll
    for (int ks=0; ks<2; ks++) {
      bf16x8 af[4], bfr[4];
      #pragma unroll
      for (int mi=0;mi<4;mi++)
        af[mi] = *(const bf16x8*)&As[(wm*64+mi*16+lr)*64 + (((ks*4+quad) ^ (lr&7))<<3)];
      #pragma unroll
      for (int ni=0;ni<4;ni++)
        bfr[ni] = *(const bf16x8*)&Bs[(wn*64+ni*16+lr)*64 + (((ks*4+quad) ^ (lr&7))<<3)];
      #pragma unroll
      for (int mi=0;mi<4;mi++)
        #pragma unroll
        for (int ni=0;ni<4;ni++)
          acc[mi][ni] = __builtin_amdgcn_mfma_f32_16x16x32_bf16(af[mi], bfr[ni], acc[mi][ni], 0,0,0);
    }
    __syncthreads();
  }
  // all waves past the final barrier: Sh (As/Bs) is dead, reusable.

  if (MODE==1) {
    #pragma unroll
    for (int mi=0;mi<4;mi++) {
      int row = m0 + wm*64 + mi*16 + quad*4;
      #pragma unroll
      for (int ni=0;ni<4;ni++) {
        int col = n0 + wn*64 + ni*16 + lr;
        #pragma unroll
        for (int r=0;r<4;r++)
          Cf[(size_t)(row+r)*ND + col] = acc[mi][ni][r];
      }
    }
  } else if (z < 2) {
    bf16_t* Cb = (z==0) ? C0 : C1;
    const float sc = (z==0) ? 0.18033688011112042f : 1.0f;  // 0.125*log2(e)
    #pragma unroll
    for (int mi=0;mi<4;mi++) {
      int row = m0 + wm*64 + mi*16 + quad*4;
      int l = row & 2047;
      #pragma unroll
      for (int ni=0;ni<2;ni++) {
        int col = n0 + wn*64 + ni*16 + lr;
        int f = ni*16 + lr;
        #pragma unroll
        for (int r=0;r<4;r++) {
          float c = cosT[(l+r)*32 + f];
          float s = sinT[(l+r)*32 + f];
          float lo = acc[mi][ni][r], hi = acc[mi][ni+2][r];
          Cb[(size_t)(row+r)*ND + col]      = (bf16_t)((lo*c - hi*s)*sc);
          Cb[(size_t)(row+r)*ND + col + 32] = (bf16_t)((hi*c + lo*s)*sc);
        }
      }
    }
  } else {
    // --- Vt epilogue via LDS transpose (coalesced stores) ---
    // Ts[coln][rowm'] 128x128 bf16 = 32KB (== Sh). XOR swizzle on rowm with
    // bits>=3 only: preserves the b64 4-run (write) and b128 8-run (read);
    // makes write banks 2-way max (free) and breaks the 256B-stride pattern.
    #pragma unroll
    for (int mi=0;mi<4;mi++) {
      int rowm = wm*64 + mi*16 + quad*4;
      #pragma unroll
      for (int ni=0;ni<4;ni++) {
        int coln = wn*64 + ni*16 + lr;
        uint2 val;
        val.x = pack_bf16(acc[mi][ni][0], acc[mi][ni][1]);
        val.y = pack_bf16(acc[mi][ni][2], acc[mi][ni][3]);
        *(uint2*)&Sh[coln*128 + (rowm ^ ((coln&15)<<3))] = val;
      }
    }
    __syncthreads();
    int bb = m0 >> 11, l0 = m0 & 2047;
    #pragma unroll
    for (int rep=0; rep<8; rep++) {
      int idx = rep*256 + tid;
      int coln = idx >> 4, seg = idx & 15;      // 128 n-rows x 16 L-segments
      bf16x8 v = *(const bf16x8*)&Sh[coln*128 + ((seg*8) ^ ((coln&15)<<3))];
      int cg = n0 + coln;                       // global head-dim column
      *(bf16x8*)&C2[((size_t)((bb<<4) + (cg>>6))*64 + (cg&63))*2048 + l0 + seg*8] = v;
    }
  }
}

// ------------------------------ flash attention v11 ------------------------
// grid (64,16): x=bh (XCD-local), y=q128. KVBLK=64, ring-3 (48KB), 2-deep
// prefetch, counted vmcnt(4). v11: kv-loop unrolled x3 so the ring index is
// compile-time (LDS addrs fold to base+offset imm); cvt_pk inline asm.
// FROZEN: R7 prediction matched (issue-bound; diet -8%).
__global__ __launch_bounds__(256) void attn_kernel(
    const bf16_t* __restrict__ Q, const bf16_t* __restrict__ K,
    const bf16_t* __restrict__ Vt, bf16_t* __restrict__ O)
{
  __shared__ __align__(16) bf16_t Ks[3][4096];   // 64kv x 64d  (8KB x3)
  __shared__ __align__(16) bf16_t Vs[3][4096];   // 64d  x 64kv (8KB x3)
  int tid = threadIdx.x;
  int wave = tid>>6, lane = tid&63, quad = lane>>4, lr = lane&15;
  int bh = blockIdx.x; int b = bh>>4, h = bh&15;
  int q0 = blockIdx.y*128 + wave*32;
  size_t rowQ = (size_t)b*L_ + q0;

  int slr = (lr&3) | ((lr&4)<<1) | ((lr&8)>>1);
  int srow8 = lane>>3;
  int sslot = lane&7;

  bf16x8 qf[2][2];
  #pragma unroll
  for (int n=0;n<2;n++)
    #pragma unroll
    for (int ks=0;ks<2;ks++)
      qf[n][ks] = *(const bf16x8*)&Q[(rowQ + n*16 + lr)*D_ + h*HD_ + ks*32 + quad*8];

  const bf16_t* Kg = K + (size_t)b*L_*D_ + h*HD_;
  const bf16_t* Vg = Vt + (size_t)bh*HD_*L_;

  bf16x8 onesf;
  #pragma unroll
  for (int j=0;j<8;j++) onesf[j] = (bf16_t)1.0f;

  floatx4 zero4 = {0.f,0.f,0.f,0.f};
  floatx4 accO[2][4];
  floatx4 accS[2];
  accS[0] = zero4; accS[1] = zero4;
  #pragma unroll
  for (int n=0;n<2;n++)
    #pragma unroll
    for (int dt=0;dt<4;dt++) accO[n][dt] = zero4;

  auto stage = [&](int it, int c) {
    #pragma unroll
    for (int j=0;j<2;j++) {
      int row = wave*16 + j*8 + srow8;
      int col = ((sslot ^ (row&7)) << 3);
      async_copy16(Kg + (size_t)(it*64 + row)*D_ + col, &Ks[c][(wave*16 + j*8)*64]);
      async_copy16(Vg + (size_t)row*L_ + it*64 + col,   &Vs[c][(wave*16 + j*8)*64]);
    }
  };

  stage(0, 0);
  stage(1, 1);
  asm volatile("s_waitcnt vmcnt(4)" ::: "memory");
  __builtin_amdgcn_s_barrier();

// One kv-iteration. CC and DO_STAGE are compile-time -> LDS ring bases fold
// into ds_read offset immediates; stage target (CC+2)%3 folds too.
#define ATTN_BODY(IT, CC, DO_STAGE)                                           \
  {                                                                           \
    if (DO_STAGE) stage((IT)+2, ((CC)+2)%3);                                  \
    floatx4 St[2][4];                                                         \
    _Pragma("unroll")                                                         \
    for (int t=0;t<4;t++) { St[0][t]=zero4; St[1][t]=zero4; }                 \
    _Pragma("unroll")                                                         \
    for (int t=0;t<4;t++) {                                                   \
      _Pragma("unroll")                                                       \
      for (int ks=0;ks<2;ks++) {                                              \
        bf16x8 kf = *(const bf16x8*)&Ks[CC][(t*16+slr)*64 + (((ks*4+quad) ^ (slr&7))<<3)]; \
        St[0][t] = __builtin_amdgcn_mfma_f32_16x16x32_bf16(kf, qf[0][ks], St[0][t], 0,0,0); \
        St[1][t] = __builtin_amdgcn_mfma_f32_16x16x32_bf16(kf, qf[1][ks], St[1][t], 0,0,0); \
      }                                                                       \
    }                                                                         \
    bf16x8 pfv[2][2];                                                         \
    _Pragma("unroll")                                                         \
    for (int n=0;n<2;n++) {                                                   \
      _Pragma("unroll")                                                       \
      for (int hh=0;hh<2;hh++) {                                              \
        unsigned int w00 = cvt_pk(exp2f(St[n][2*hh][0]),   exp2f(St[n][2*hh][1]));   \
        unsigned int w01 = cvt_pk(exp2f(St[n][2*hh][2]),   exp2f(St[n][2*hh][3]));   \
        unsigned int w10 = cvt_pk(exp2f(St[n][2*hh+1][0]), exp2f(St[n][2*hh+1][1])); \
        unsigned int w11 = cvt_pk(exp2f(St[n][2*hh+1][2]), exp2f(St[n][2*hh+1][3])); \
        u32x2 r0 = __builtin_amdgcn_permlane32_swap(w00, w10, false, false);  \
        u32x2 r1 = __builtin_amdgcn_permlane32_swap(w01, w11, false, false);  \
        union { unsigned int u[4]; bf16x8 v; } pu;                            \
        pu.u[0] = r0.x; pu.u[1] = r1.x; pu.u[2] = r0.y; pu.u[3] = r1.y;       \
        pfv[n][hh] = pu.v;                                                    \
      }                                                                       \
    }                                                                         \
    _Pragma("unroll")                                                         \
    for (int dt=0;dt<4;dt++) {                                                \
      _Pragma("unroll")                                                       \
      for (int hh=0;hh<2;hh++) {                                              \
        bf16x8 vf = *(const bf16x8*)&Vs[CC][(dt*16+lr)*64 + (((hh*4+quad) ^ (lr&7))<<3)]; \
        accO[0][dt] = __builtin_amdgcn_mfma_f32_16x16x32_bf16(vf, pfv[0][hh], accO[0][dt], 0,0,0); \
        accO[1][dt] = __builtin_amdgcn_mfma_f32_16x16x32_bf16(vf, pfv[1][hh], accO[1][dt], 0,0,0); \
      }                                                                       \
    }                                                                         \
    accS[0] = __builtin_amdgcn_mfma_f32_16x16x32_bf16(onesf, pfv[0][0], accS[0], 0,0,0); \
    accS[1] = __builtin_amdgcn_mfma_f32_16x16x32_bf16(onesf, pfv[1][0], accS[1], 0,0,0); \
    accS[0] = __builtin_amdgcn_mfma_f32_16x16x32_bf16(onesf, pfv[0][1], accS[0], 0,0,0); \
    accS[1] = __builtin_amdgcn_mfma_f32_16x16x32_bf16(onesf, pfv[1][1], accS[1], 0,0,0); \
    if (DO_STAGE) { asm volatile("s_waitcnt vmcnt(4)" ::: "memory"); }        \
    else          { asm volatile("s_waitcnt vmcnt(0)" ::: "memory"); }        \
    __builtin_amdgcn_s_barrier();                                             \
  }

  #pragma unroll 1
  for (int itb = 0; itb < 30; itb += 3) {
    ATTN_BODY(itb+0, 0, true);
    ATTN_BODY(itb+1, 1, true);
    ATTN_BODY(itb+2, 2, true);
  }
  ATTN_BODY(30, 0, false);
  ATTN_BODY(31, 1, false);
#undef ATTN_BODY

  float inv0 = 1.0f / accS[0][0];
  float inv1 = 1.0f / accS[1][0];
  #pragma unroll
  for (int n=0;n<2;n++) {
    float inv = n ? inv1 : inv0;
    #pragma unroll
    for (int dt=0;dt<4;dt++) {
      uint2 w;
      w.x = cvt_pk(accO[n][dt][0]*inv, accO[n][dt][1]*inv);
      w.y = cvt_pk(accO[n][dt][2]*inv, accO[n][dt][3]*inv);
      *(uint2*)&O[(rowQ + n*16 + lr)*D_ + h*HD_ + dt*16 + quad*4] = w;
    }
  }
}

// ------------------------------ launch -------------------------------------
extern "C" void kernel_launch(void* const* d_in, const int* in_sizes, int n_in,
                              void* d_out, int out_size, void* d_ws, size_t ws_size,
                              hipStream_t stream) {
  const float* x  = (const float*)d_in[0];
  const float* wq = (const float*)d_in[1];
  const float* wk = (const float*)d_in[2];
  const float* wv = (const float*)d_in[3];
  const float* wo = (const float*)d_in[4];

  char* ws = (char*)d_ws;
  bf16_t* xb  = (bf16_t*)(ws);                       // 16MB; reused as O after attn
  bf16_t* Qb  = (bf16_t*)(ws + (size_t)(16u<<20));
  bf16_t* Kb  = (bf16_t*)(ws + (size_t)(32u<<20));
  bf16_t* Vtb = (bf16_t*)(ws + (size_t)(48u<<20));
  bf16_t* wqb = (bf16_t*)(ws + (size_t)(64u<<20));
  bf16_t* wkb = (bf16_t*)(ws + (size_t)(66u<<20));
  bf16_t* wvb = (bf16_t*)(ws + (size_t)(68u<<20));
  bf16_t* wob = (bf16_t*)(ws + (size_t)(70u<<20));
  float* cosT = (float*)(ws + (size_t)(72u<<20));
  float* sinT = (float*)(ws + (size_t)(72u<<20) + (256u<<10));
  bf16_t* Ob = xb;

  prep_kernel<<<49408, 256, 0, stream>>>(x, wq, wk, wv, wo, xb, wqb, wkb, wvb, wob, cosT, sinT);
  gemm_kernel<0><<<dim3(8,64,3), 256, 0, stream>>>(xb, wqb, wkb, wvb, Qb, Kb, Vtb, nullptr, cosT, sinT);
  attn_kernel<<<dim3(64,16), 256, 0, stream>>>(Qb, Kb, Vtb, Ob);
  gemm_kernel<1><<<dim3(8,64,1), 256, 0, stream>>>(Ob, wob, nullptr, nullptr,
                                                   nullptr, nullptr, nullptr, (float*)d_out, cosT, sinT);
}

// Round 9
// 302.817 us; speedup vs baseline: 1.1660x; 1.0337x over previous
//
#include <hip/hip_runtime.h>

// ---------------------------------------------------------------------------
// MultiHeadSelfAttention  B=4 L=2048 D=1024 H=16 hd=64, fp32 in/out.
//   prep:      x,W -> bf16; rope tables ([f][l] layout, R9)
//   gemm v1.2: v1.1 + (a) T1 XCD grid swap: grid (64,8,z), m0=blockIdx.x ->
//              the 8 blocks sharing an A-panel land on ONE XCD (A-panels
//              L2-resident, reused 24x; was refetched from L3 by all 8 XCDs).
//              (b) RoPE tables transposed to [f][l] -> epilogue loads are 16
//              float4 instead of 64 scalar f32. Values bit-identical.
//   attn v11:  FROZEN (R7: issue-diet win; R8's 143us reading = throttled
//              node, identical source).
//   gemm<1>:   d_out = O @ Wo^T (same swap applied)
// History: R6 ring/BK32 regressed (occupancy>ILP); R4/R5 512thr/144KB killed
// container; R7 diet -8% attn; R8 Vt-transpose epilogue +~4us net.
// ---------------------------------------------------------------------------

typedef __bf16 bf16_t;
typedef __bf16 bf16x8 __attribute__((ext_vector_type(8)));
typedef __bf16 bf16x4 __attribute__((ext_vector_type(4)));
typedef float  floatx4 __attribute__((ext_vector_type(4)));
typedef unsigned int u32x2 __attribute__((ext_vector_type(2)));

#define B_  4
#define L_  2048
#define D_  1024
#define H_  16
#define HD_ 64
#define M_  (B_*L_)

__device__ __forceinline__ void async_copy16(const bf16_t* g, bf16_t* l) {
  __builtin_amdgcn_global_load_lds(
      (const __attribute__((address_space(1))) void*)g,
      (__attribute__((address_space(3))) void*)l, 16, 0, 0);
}

__device__ __forceinline__ unsigned int pack_bf16(float a, float b) {
  unsigned short ua = __builtin_bit_cast(unsigned short, (bf16_t)a);
  unsigned short ub = __builtin_bit_cast(unsigned short, (bf16_t)b);
  return (unsigned int)ua | ((unsigned int)ub << 16);
}

// single-instruction packed f32x2 -> bf16x2 (RTNE), no gfx950 builtin (m240)
__device__ __forceinline__ unsigned int cvt_pk(float lo, float hi) {
  unsigned int r;
  asm("v_cvt_pk_bf16_f32 %0, %1, %2" : "=v"(r) : "v"(lo), "v"(hi));
  return r;
}

// ------------------------------ prep ---------------------------------------
__global__ void prep_kernel(const float* __restrict__ x,
                            const float* __restrict__ wq, const float* __restrict__ wk,
                            const float* __restrict__ wv, const float* __restrict__ wo,
                            bf16_t* __restrict__ xb,
                            bf16_t* __restrict__ wqb, bf16_t* __restrict__ wkb,
                            bf16_t* __restrict__ wvb, bf16_t* __restrict__ wob,
                            float* __restrict__ cosT, float* __restrict__ sinT)
{
  const int NX = M_*D_;
  const int NW = D_*D_;
  int i = blockIdx.x*256 + threadIdx.x;
  if (i < NX) { xb[i] = (bf16_t)x[i]; return; }
  i -= NX;
  if (i < NW) { wqb[i] = (bf16_t)wq[i]; return; }
  i -= NW;
  if (i < NW) { wkb[i] = (bf16_t)wk[i]; return; }
  i -= NW;
  if (i < NW) { wvb[i] = (bf16_t)wv[i]; return; }
  i -= NW;
  if (i < NW) { wob[i] = (bf16_t)wo[i]; return; }
  i -= NW;
  if (i < L_*32) {
    // [f][l] layout: i = f*2048 + l. Consecutive i -> consecutive l (coalesced).
    int f = i >> 11, l = i & 2047;
    double inv = pow(10000.0, -(double)f / 32.0);
    double ang = (double)l * inv;
    cosT[i] = (float)cos(ang);
    sinT[i] = (float)sin(ang);
  }
}

// ------------------------------ GEMM v1.2 (C = A * W^T) --------------------
// Grid (64, 8, z): m0 = blockIdx.x*128 (T1: same-A-panel blocks differ by 64
// in linear ID == 0 mod 8 -> same XCD -> A-panel L2-resident, 24x reuse).
template<int MODE>
__global__ __launch_bounds__(256) void gemm_kernel(
    const bf16_t* __restrict__ A,
    const bf16_t* __restrict__ W0, const bf16_t* __restrict__ W1, const bf16_t* __restrict__ W2,
    bf16_t* __restrict__ C0, bf16_t* __restrict__ C1, bf16_t* __restrict__ C2,
    float* __restrict__ Cf,
    const float* __restrict__ cosT, const float* __restrict__ sinT)
{
  __shared__ __align__(16) bf16_t Sh[16384];   // As = Sh[0:8192), Bs = Sh[8192:)
  bf16_t* As = Sh;
  bf16_t* Bs = Sh + 8192;
  const int KD = 1024, ND = 1024;
  int z = (MODE==0) ? (int)blockIdx.z : 0;
  const bf16_t* W = (MODE==1) ? W0 : (z==0 ? W0 : (z==1 ? W1 : W2));
  int m0 = blockIdx.x*128, n0 = blockIdx.y*128;
  int tid = threadIdx.x;
  int wave = tid>>6, lane = tid&63, quad = lane>>4, lr = lane&15;
  int wm = wave>>1, wn = wave&1;
  int srow = lane>>3, sslot = lane&7;

  floatx4 zero4 = {0.f,0.f,0.f,0.f};
  floatx4 acc[4][4];
  #pragma unroll
  for (int i=0;i<4;i++)
    #pragma unroll
    for (int j=0;j<4;j++) acc[i][j] = zero4;

  #pragma unroll 1
  for (int k0 = 0; k0 < KD; k0 += 64) {
    #pragma unroll
    for (int j=0;j<4;j++) {
      int chunk = wave + j*4;
      int row = chunk*8 + srow;
      int col = ((sslot ^ (row&7)) << 3);
      async_copy16(A + (size_t)(m0+row)*KD + k0 + col, &As[chunk*512]);
      async_copy16(W + (size_t)(n0+row)*KD + k0 + col, &Bs[chunk*512]);
    }
    __syncthreads();
    #pragma unroll
    for (int ks=0; ks<2; ks++) {
      bf16x8 af[4], bfr[4];
      #pragma unroll
      for (int mi=0;mi<4;mi++)
        af[mi] = *(const bf16x8*)&As[(wm*64+mi*16+lr)*64 + (((ks*4+quad) ^ (lr&7))<<3)];
      #pragma unroll
      for (int ni=0;ni<4;ni++)
        bfr[ni] = *(const bf16x8*)&Bs[(wn*64+ni*16+lr)*64 + (((ks*4+quad) ^ (lr&7))<<3)];
      #pragma unroll
      for (int mi=0;mi<4;mi++)
        #pragma unroll
        for (int ni=0;ni<4;ni++)
          acc[mi][ni] = __builtin_amdgcn_mfma_f32_16x16x32_bf16(af[mi], bfr[ni], acc[mi][ni], 0,0,0);
    }
    __syncthreads();
  }
  // all waves past the final barrier: Sh (As/Bs) is dead, reusable.

  if (MODE==1) {
    #pragma unroll
    for (int mi=0;mi<4;mi++) {
      int row = m0 + wm*64 + mi*16 + quad*4;
      #pragma unroll
      for (int ni=0;ni<4;ni++) {
        int col = n0 + wn*64 + ni*16 + lr;
        #pragma unroll
        for (int r=0;r<4;r++)
          Cf[(size_t)(row+r)*ND + col] = acc[mi][ni][r];
      }
    }
  } else if (z < 2) {
    bf16_t* Cb = (z==0) ? C0 : C1;
    const float sc = (z==0) ? 0.18033688011112042f : 1.0f;  // 0.125*log2(e)
    #pragma unroll
    for (int mi=0;mi<4;mi++) {
      int row = m0 + wm*64 + mi*16 + quad*4;
      int l = row & 2047;
      #pragma unroll
      for (int ni=0;ni<2;ni++) {
        int col = n0 + wn*64 + ni*16 + lr;
        int f = ni*16 + lr;
        // [f][l] tables: r=0..3 contiguous -> one float4 each (bit-identical).
        float4 cv = *(const float4*)&cosT[f*2048 + l];
        float4 sv = *(const float4*)&sinT[f*2048 + l];
        #pragma unroll
        for (int r=0;r<4;r++) {
          float c = (&cv.x)[r];
          float s = (&sv.x)[r];
          float lo = acc[mi][ni][r], hi = acc[mi][ni+2][r];
          Cb[(size_t)(row+r)*ND + col]      = (bf16_t)((lo*c - hi*s)*sc);
          Cb[(size_t)(row+r)*ND + col + 32] = (bf16_t)((hi*c + lo*s)*sc);
        }
      }
    }
  } else {
    // --- Vt epilogue via LDS transpose (coalesced stores), R8 ---
    #pragma unroll
    for (int mi=0;mi<4;mi++) {
      int rowm = wm*64 + mi*16 + quad*4;
      #pragma unroll
      for (int ni=0;ni<4;ni++) {
        int coln = wn*64 + ni*16 + lr;
        uint2 val;
        val.x = pack_bf16(acc[mi][ni][0], acc[mi][ni][1]);
        val.y = pack_bf16(acc[mi][ni][2], acc[mi][ni][3]);
        *(uint2*)&Sh[coln*128 + (rowm ^ ((coln&15)<<3))] = val;
      }
    }
    __syncthreads();
    int bb = m0 >> 11, l0 = m0 & 2047;
    #pragma unroll
    for (int rep=0; rep<8; rep++) {
      int idx = rep*256 + tid;
      int coln = idx >> 4, seg = idx & 15;      // 128 n-rows x 16 L-segments
      bf16x8 v = *(const bf16x8*)&Sh[coln*128 + ((seg*8) ^ ((coln&15)<<3))];
      int cg = n0 + coln;                       // global head-dim column
      *(bf16x8*)&C2[((size_t)((bb<<4) + (cg>>6))*64 + (cg&63))*2048 + l0 + seg*8] = v;
    }
  }
}

// ------------------------------ flash attention v11 ------------------------
// grid (64,16): x=bh (XCD-local), y=q128. KVBLK=64, ring-3 (48KB), 2-deep
// prefetch, counted vmcnt(4). v11: kv-loop unrolled x3 so the ring index is
// compile-time (LDS addrs fold to base+offset imm); cvt_pk inline asm.
// FROZEN: R7 prediction matched (issue-bound; diet -8%).
__global__ __launch_bounds__(256) void attn_kernel(
    const bf16_t* __restrict__ Q, const bf16_t* __restrict__ K,
    const bf16_t* __restrict__ Vt, bf16_t* __restrict__ O)
{
  __shared__ __align__(16) bf16_t Ks[3][4096];   // 64kv x 64d  (8KB x3)
  __shared__ __align__(16) bf16_t Vs[3][4096];   // 64d  x 64kv (8KB x3)
  int tid = threadIdx.x;
  int wave = tid>>6, lane = tid&63, quad = lane>>4, lr = lane&15;
  int bh = blockIdx.x; int b = bh>>4, h = bh&15;
  int q0 = blockIdx.y*128 + wave*32;
  size_t rowQ = (size_t)b*L_ + q0;

  int slr = (lr&3) | ((lr&4)<<1) | ((lr&8)>>1);
  int srow8 = lane>>3;
  int sslot = lane&7;

  bf16x8 qf[2][2];
  #pragma unroll
  for (int n=0;n<2;n++)
    #pragma unroll
    for (int ks=0;ks<2;ks++)
      qf[n][ks] = *(const bf16x8*)&Q[(rowQ + n*16 + lr)*D_ + h*HD_ + ks*32 + quad*8];

  const bf16_t* Kg = K + (size_t)b*L_*D_ + h*HD_;
  const bf16_t* Vg = Vt + (size_t)bh*HD_*L_;

  bf16x8 onesf;
  #pragma unroll
  for (int j=0;j<8;j++) onesf[j] = (bf16_t)1.0f;

  floatx4 zero4 = {0.f,0.f,0.f,0.f};
  floatx4 accO[2][4];
  floatx4 accS[2];
  accS[0] = zero4; accS[1] = zero4;
  #pragma unroll
  for (int n=0;n<2;n++)
    #pragma unroll
    for (int dt=0;dt<4;dt++) accO[n][dt] = zero4;

  auto stage = [&](int it, int c) {
    #pragma unroll
    for (int j=0;j<2;j++) {
      int row = wave*16 + j*8 + srow8;
      int col = ((sslot ^ (row&7)) << 3);
      async_copy16(Kg + (size_t)(it*64 + row)*D_ + col, &Ks[c][(wave*16 + j*8)*64]);
      async_copy16(Vg + (size_t)row*L_ + it*64 + col,   &Vs[c][(wave*16 + j*8)*64]);
    }
  };

  stage(0, 0);
  stage(1, 1);
  asm volatile("s_waitcnt vmcnt(4)" ::: "memory");
  __builtin_amdgcn_s_barrier();

// One kv-iteration. CC and DO_STAGE are compile-time -> LDS ring bases fold
// into ds_read offset immediates; stage target (CC+2)%3 folds too.
#define ATTN_BODY(IT, CC, DO_STAGE)                                           \
  {                                                                           \
    if (DO_STAGE) stage((IT)+2, ((CC)+2)%3);                                  \
    floatx4 St[2][4];                                                         \
    _Pragma("unroll")                                                         \
    for (int t=0;t<4;t++) { St[0][t]=zero4; St[1][t]=zero4; }                 \
    _Pragma("unroll")                                                         \
    for (int t=0;t<4;t++) {                                                   \
      _Pragma("unroll")                                                       \
      for (int ks=0;ks<2;ks++) {                                              \
        bf16x8 kf = *(const bf16x8*)&Ks[CC][(t*16+slr)*64 + (((ks*4+quad) ^ (slr&7))<<3)]; \
        St[0][t] = __builtin_amdgcn_mfma_f32_16x16x32_bf16(kf, qf[0][ks], St[0][t], 0,0,0); \
        St[1][t] = __builtin_amdgcn_mfma_f32_16x16x32_bf16(kf, qf[1][ks], St[1][t], 0,0,0); \
      }                                                                       \
    }                                                                         \
    bf16x8 pfv[2][2];                                                         \
    _Pragma("unroll")                                                         \
    for (int n=0;n<2;n++) {                                                   \
      _Pragma("unroll")                                                       \
      for (int hh=0;hh<2;hh++) {                                              \
        unsigned int w00 = cvt_pk(exp2f(St[n][2*hh][0]),   exp2f(St[n][2*hh][1]));   \
        unsigned int w01 = cvt_pk(exp2f(St[n][2*hh][2]),   exp2f(St[n][2*hh][3]));   \
        unsigned int w10 = cvt_pk(exp2f(St[n][2*hh+1][0]), exp2f(St[n][2*hh+1][1])); \
        unsigned int w11 = cvt_pk(exp2f(St[n][2*hh+1][2]), exp2f(St[n][2*hh+1][3])); \
        u32x2 r0 = __builtin_amdgcn_permlane32_swap(w00, w10, false, false);  \
        u32x2 r1 = __builtin_amdgcn_permlane32_swap(w01, w11, false, false);  \
        union { unsigned int u[4]; bf16x8 v; } pu;                            \
        pu.u[0] = r0.x; pu.u[1] = r1.x; pu.u[2] = r0.y; pu.u[3] = r1.y;       \
        pfv[n][hh] = pu.v;                                                    \
      }                                                                       \
    }                                                                         \
    _Pragma("unroll")                                                         \
    for (int dt=0;dt<4;dt++) {                                                \
      _Pragma("unroll")                                                       \
      for (int hh=0;hh<2;hh++) {                                              \
        bf16x8 vf = *(const bf16x8*)&Vs[CC][(dt*16+lr)*64 + (((hh*4+quad) ^ (lr&7))<<3)]; \
        accO[0][dt] = __builtin_amdgcn_mfma_f32_16x16x32_bf16(vf, pfv[0][hh], accO[0][dt], 0,0,0); \
        accO[1][dt] = __builtin_amdgcn_mfma_f32_16x16x32_bf16(vf, pfv[1][hh], accO[1][dt], 0,0,0); \
      }                                                                       \
    }                                                                         \
    accS[0] = __builtin_amdgcn_mfma_f32_16x16x32_bf16(onesf, pfv[0][0], accS[0], 0,0,0); \
    accS[1] = __builtin_amdgcn_mfma_f32_16x16x32_bf16(onesf, pfv[1][0], accS[1], 0,0,0); \
    accS[0] = __builtin_amdgcn_mfma_f32_16x16x32_bf16(onesf, pfv[0][1], accS[0], 0,0,0); \
    accS[1] = __builtin_amdgcn_mfma_f32_16x16x32_bf16(onesf, pfv[1][1], accS[1], 0,0,0); \
    if (DO_STAGE) { asm volatile("s_waitcnt vmcnt(4)" ::: "memory"); }        \
    else          { asm volatile("s_waitcnt vmcnt(0)" ::: "memory"); }        \
    __builtin_amdgcn_s_barrier();                                             \
  }

  #pragma unroll 1
  for (int itb = 0; itb < 30; itb += 3) {
    ATTN_BODY(itb+0, 0, true);
    ATTN_BODY(itb+1, 1, true);
    ATTN_BODY(itb+2, 2, true);
  }
  ATTN_BODY(30, 0, false);
  ATTN_BODY(31, 1, false);
#undef ATTN_BODY

  float inv0 = 1.0f / accS[0][0];
  float inv1 = 1.0f / accS[1][0];
  #pragma unroll
  for (int n=0;n<2;n++) {
    float inv = n ? inv1 : inv0;
    #pragma unroll
    for (int dt=0;dt<4;dt++) {
      uint2 w;
      w.x = cvt_pk(accO[n][dt][0]*inv, accO[n][dt][1]*inv);
      w.y = cvt_pk(accO[n][dt][2]*inv, accO[n][dt][3]*inv);
      *(uint2*)&O[(rowQ + n*16 + lr)*D_ + h*HD_ + dt*16 + quad*4] = w;
    }
  }
}

// ------------------------------ launch -------------------------------------
extern "C" void kernel_launch(void* const* d_in, const int* in_sizes, int n_in,
                              void* d_out, int out_size, void* d_ws, size_t ws_size,
                              hipStream_t stream) {
  const float* x  = (const float*)d_in[0];
  const float* wq = (const float*)d_in[1];
  const float* wk = (const float*)d_in[2];
  const float* wv = (const float*)d_in[3];
  const float* wo = (const float*)d_in[4];

  char* ws = (char*)d_ws;
  bf16_t* xb  = (bf16_t*)(ws);                       // 16MB; reused as O after attn
  bf16_t* Qb  = (bf16_t*)(ws + (size_t)(16u<<20));
  bf16_t* Kb  = (bf16_t*)(ws + (size_t)(32u<<20));
  bf16_t* Vtb = (bf16_t*)(ws + (size_t)(48u<<20));
  bf16_t* wqb = (bf16_t*)(ws + (size_t)(64u<<20));
  bf16_t* wkb = (bf16_t*)(ws + (size_t)(66u<<20));
  bf16_t* wvb = (bf16_t*)(ws + (size_t)(68u<<20));
  bf16_t* wob = (bf16_t*)(ws + (size_t)(70u<<20));
  float* cosT = (float*)(ws + (size_t)(72u<<20));
  float* sinT = (float*)(ws + (size_t)(72u<<20) + (256u<<10));
  bf16_t* Ob = xb;

  prep_kernel<<<49408, 256, 0, stream>>>(x, wq, wk, wv, wo, xb, wqb, wkb, wvb, wob, cosT, sinT);
  gemm_kernel<0><<<dim3(64,8,3), 256, 0, stream>>>(xb, wqb, wkb, wvb, Qb, Kb, Vtb, nullptr, cosT, sinT);
  attn_kernel<<<dim3(64,16), 256, 0, stream>>>(Qb, Kb, Vtb, Ob);
  gemm_kernel<1><<<dim3(64,8,1), 256, 0, stream>>>(Ob, wob, nullptr, nullptr,
                                                   nullptr, nullptr, nullptr, (float*)d_out, cosT, sinT);
}

// Round 10
// 288.874 us; speedup vs baseline: 1.2223x; 1.0483x over previous
//
#include <hip/hip_runtime.h>

// ---------------------------------------------------------------------------
// MultiHeadSelfAttention  B=4 L=2048 D=1024 H=16 hd=64, fp32 in/out.
//   prep v2:   vectorized bf16 conversion (8 elem/thread, float4 x2 -> bf16x8,
//              G13); rope tables [f][l].
//   gemm v1.2: FROZEN (R9 win: T1 XCD grid swap + float4 rope loads).
//   attn v12:  T15 cross-tile pipeline: during iter it, QK^T(tile it+1) (MFMA)
//              overlaps softmax(tile it) (VALU/trans) in-wave. St doubled to
//              StA/StB, static indexing via 6-iter macro cycle (ring-3 x
//              parity-2). End-of-iter wait -> vmcnt(0) (1-body cover, K/V
//              L2-resident). Theory: attn is per-wave dependency-chain bound
//              (no pipe saturated; R7 diet confirmed issue/chain regime).
//   gemm<1>:   d_out = O @ Wo^T
// History: R6 ring/BK32 regressed; R4/R5 512thr/144KB killed container; R7
// diet -8% attn; R8 Vt-transpose +4; R9 T1 swap -16 gemm-side.
// ---------------------------------------------------------------------------

typedef __bf16 bf16_t;
typedef __bf16 bf16x8 __attribute__((ext_vector_type(8)));
typedef __bf16 bf16x4 __attribute__((ext_vector_type(4)));
typedef float  floatx4 __attribute__((ext_vector_type(4)));
typedef unsigned int u32x2 __attribute__((ext_vector_type(2)));

#define B_  4
#define L_  2048
#define D_  1024
#define H_  16
#define HD_ 64
#define M_  (B_*L_)

__device__ __forceinline__ void async_copy16(const bf16_t* g, bf16_t* l) {
  __builtin_amdgcn_global_load_lds(
      (const __attribute__((address_space(1))) void*)g,
      (__attribute__((address_space(3))) void*)l, 16, 0, 0);
}

__device__ __forceinline__ unsigned int pack_bf16(float a, float b) {
  unsigned short ua = __builtin_bit_cast(unsigned short, (bf16_t)a);
  unsigned short ub = __builtin_bit_cast(unsigned short, (bf16_t)b);
  return (unsigned int)ua | ((unsigned int)ub << 16);
}

// single-instruction packed f32x2 -> bf16x2 (RTNE), no gfx950 builtin (m240)
__device__ __forceinline__ unsigned int cvt_pk(float lo, float hi) {
  unsigned int r;
  asm("v_cvt_pk_bf16_f32 %0, %1, %2" : "=v"(r) : "v"(lo), "v"(hi));
  return r;
}

// ------------------------------ prep v2 ------------------------------------
__global__ void prep_kernel(const float* __restrict__ x,
                            const float* __restrict__ wq, const float* __restrict__ wk,
                            const float* __restrict__ wv, const float* __restrict__ wo,
                            bf16_t* __restrict__ xb,
                            bf16_t* __restrict__ wqb, bf16_t* __restrict__ wkb,
                            bf16_t* __restrict__ wvb, bf16_t* __restrict__ wob,
                            float* __restrict__ cosT, float* __restrict__ sinT)
{
  const int NXv = (M_*D_) >> 3;        // 1<<20 vec8 groups of x
  const int NWv = (D_*D_) >> 3;        // 1<<17 vec8 groups per W
  const int NC  = NXv + 4*NWv;         // 1,572,864
  int i = blockIdx.x*256 + threadIdx.x;
  if (i < NC) {
    const float* s; bf16_t* d; size_t o;
    if (i < NXv) { s = x; d = xb; o = (size_t)i << 3; }
    else {
      int r = i - NXv; int w = r >> 17;
      o = (size_t)(r & (NWv-1)) << 3;
      s = (w==0)?wq:(w==1)?wk:(w==2)?wv:wo;
      d = (w==0)?wqb:(w==1)?wkb:(w==2)?wvb:wob;
    }
    float4 a = *(const float4*)(s+o);
    float4 b = *(const float4*)(s+o+4);
    bf16x8 v;
    v[0]=(bf16_t)a.x; v[1]=(bf16_t)a.y; v[2]=(bf16_t)a.z; v[3]=(bf16_t)a.w;
    v[4]=(bf16_t)b.x; v[5]=(bf16_t)b.y; v[6]=(bf16_t)b.z; v[7]=(bf16_t)b.w;
    *(bf16x8*)(d+o) = v;
    return;
  }
  i -= NC;
  if (i < L_*32) {
    // [f][l] layout: i = f*2048 + l (coalesced writes).
    int f = i >> 11, l = i & 2047;
    double inv = pow(10000.0, -(double)f / 32.0);
    double ang = (double)l * inv;
    cosT[i] = (float)cos(ang);
    sinT[i] = (float)sin(ang);
  }
}

// ------------------------------ GEMM v1.2 (C = A * W^T) --------------------
// Grid (64, 8, z): m0 = blockIdx.x*128 (T1: same-A-panel blocks -> same XCD).
template<int MODE>
__global__ __launch_bounds__(256) void gemm_kernel(
    const bf16_t* __restrict__ A,
    const bf16_t* __restrict__ W0, const bf16_t* __restrict__ W1, const bf16_t* __restrict__ W2,
    bf16_t* __restrict__ C0, bf16_t* __restrict__ C1, bf16_t* __restrict__ C2,
    float* __restrict__ Cf,
    const float* __restrict__ cosT, const float* __restrict__ sinT)
{
  __shared__ __align__(16) bf16_t Sh[16384];   // As = Sh[0:8192), Bs = Sh[8192:)
  bf16_t* As = Sh;
  bf16_t* Bs = Sh + 8192;
  const int KD = 1024, ND = 1024;
  int z = (MODE==0) ? (int)blockIdx.z : 0;
  const bf16_t* W = (MODE==1) ? W0 : (z==0 ? W0 : (z==1 ? W1 : W2));
  int m0 = blockIdx.x*128, n0 = blockIdx.y*128;
  int tid = threadIdx.x;
  int wave = tid>>6, lane = tid&63, quad = lane>>4, lr = lane&15;
  int wm = wave>>1, wn = wave&1;
  int srow = lane>>3, sslot = lane&7;

  floatx4 zero4 = {0.f,0.f,0.f,0.f};
  floatx4 acc[4][4];
  #pragma unroll
  for (int i=0;i<4;i++)
    #pragma unroll
    for (int j=0;j<4;j++) acc[i][j] = zero4;

  #pragma unroll 1
  for (int k0 = 0; k0 < KD; k0 += 64) {
    #pragma unroll
    for (int j=0;j<4;j++) {
      int chunk = wave + j*4;
      int row = chunk*8 + srow;
      int col = ((sslot ^ (row&7)) << 3);
      async_copy16(A + (size_t)(m0+row)*KD + k0 + col, &As[chunk*512]);
      async_copy16(W + (size_t)(n0+row)*KD + k0 + col, &Bs[chunk*512]);
    }
    __syncthreads();
    #pragma unroll
    for (int ks=0; ks<2; ks++) {
      bf16x8 af[4], bfr[4];
      #pragma unroll
      for (int mi=0;mi<4;mi++)
        af[mi] = *(const bf16x8*)&As[(wm*64+mi*16+lr)*64 + (((ks*4+quad) ^ (lr&7))<<3)];
      #pragma unroll
      for (int ni=0;ni<4;ni++)
        bfr[ni] = *(const bf16x8*)&Bs[(wn*64+ni*16+lr)*64 + (((ks*4+quad) ^ (lr&7))<<3)];
      #pragma unroll
      for (int mi=0;mi<4;mi++)
        #pragma unroll
        for (int ni=0;ni<4;ni++)
          acc[mi][ni] = __builtin_amdgcn_mfma_f32_16x16x32_bf16(af[mi], bfr[ni], acc[mi][ni], 0,0,0);
    }
    __syncthreads();
  }
  // all waves past the final barrier: Sh (As/Bs) is dead, reusable.

  if (MODE==1) {
    #pragma unroll
    for (int mi=0;mi<4;mi++) {
      int row = m0 + wm*64 + mi*16 + quad*4;
      #pragma unroll
      for (int ni=0;ni<4;ni++) {
        int col = n0 + wn*64 + ni*16 + lr;
        #pragma unroll
        for (int r=0;r<4;r++)
          Cf[(size_t)(row+r)*ND + col] = acc[mi][ni][r];
      }
    }
  } else if (z < 2) {
    bf16_t* Cb = (z==0) ? C0 : C1;
    const float sc = (z==0) ? 0.18033688011112042f : 1.0f;  // 0.125*log2(e)
    #pragma unroll
    for (int mi=0;mi<4;mi++) {
      int row = m0 + wm*64 + mi*16 + quad*4;
      int l = row & 2047;
      #pragma unroll
      for (int ni=0;ni<2;ni++) {
        int col = n0 + wn*64 + ni*16 + lr;
        int f = ni*16 + lr;
        float4 cv = *(const float4*)&cosT[f*2048 + l];
        float4 sv = *(const float4*)&sinT[f*2048 + l];
        #pragma unroll
        for (int r=0;r<4;r++) {
          float c = (&cv.x)[r];
          float s = (&sv.x)[r];
          float lo = acc[mi][ni][r], hi = acc[mi][ni+2][r];
          Cb[(size_t)(row+r)*ND + col]      = (bf16_t)((lo*c - hi*s)*sc);
          Cb[(size_t)(row+r)*ND + col + 32] = (bf16_t)((hi*c + lo*s)*sc);
        }
      }
    }
  } else {
    // --- Vt epilogue via LDS transpose (coalesced stores), R8 ---
    #pragma unroll
    for (int mi=0;mi<4;mi++) {
      int rowm = wm*64 + mi*16 + quad*4;
      #pragma unroll
      for (int ni=0;ni<4;ni++) {
        int coln = wn*64 + ni*16 + lr;
        uint2 val;
        val.x = pack_bf16(acc[mi][ni][0], acc[mi][ni][1]);
        val.y = pack_bf16(acc[mi][ni][2], acc[mi][ni][3]);
        *(uint2*)&Sh[coln*128 + (rowm ^ ((coln&15)<<3))] = val;
      }
    }
    __syncthreads();
    int bb = m0 >> 11, l0 = m0 & 2047;
    #pragma unroll
    for (int rep=0; rep<8; rep++) {
      int idx = rep*256 + tid;
      int coln = idx >> 4, seg = idx & 15;
      bf16x8 v = *(const bf16x8*)&Sh[coln*128 + ((seg*8) ^ ((coln&15)<<3))];
      int cg = n0 + coln;
      *(bf16x8*)&C2[((size_t)((bb<<4) + (cg>>6))*64 + (cg&63))*2048 + l0 + seg*8] = v;
    }
  }
}

// ------------------------------ flash attention v12 ------------------------
// grid (64,16): x=bh (XCD-local), y=q128. KVBLK=64, ring-3 (48KB).
// T15 pipeline: iter it does softmax(St_cur=tile it) || QK^T(tile it+1 ->
// St_next) || PV(tile it). Invariant at iter start: tiles <= it+1 landed
// (vmcnt(0)+barrier at prev iter end; stage(it+2) gets 1 body of cover,
// K/V L2-resident). StA/StB static alternation (rule #20), 6-iter cycle.
__global__ __launch_bounds__(256) void attn_kernel(
    const bf16_t* __restrict__ Q, const bf16_t* __restrict__ K,
    const bf16_t* __restrict__ Vt, bf16_t* __restrict__ O)
{
  __shared__ __align__(16) bf16_t Ks[3][4096];   // 64kv x 64d  (8KB x3)
  __shared__ __align__(16) bf16_t Vs[3][4096];   // 64d  x 64kv (8KB x3)
  int tid = threadIdx.x;
  int wave = tid>>6, lane = tid&63, quad = lane>>4, lr = lane&15;
  int bh = blockIdx.x; int b = bh>>4, h = bh&15;
  int q0 = blockIdx.y*128 + wave*32;
  size_t rowQ = (size_t)b*L_ + q0;

  int slr = (lr&3) | ((lr&4)<<1) | ((lr&8)>>1);
  int srow8 = lane>>3;
  int sslot = lane&7;

  bf16x8 qf[2][2];
  #pragma unroll
  for (int n=0;n<2;n++)
    #pragma unroll
    for (int ks=0;ks<2;ks++)
      qf[n][ks] = *(const bf16x8*)&Q[(rowQ + n*16 + lr)*D_ + h*HD_ + ks*32 + quad*8];

  const bf16_t* Kg = K + (size_t)b*L_*D_ + h*HD_;
  const bf16_t* Vg = Vt + (size_t)bh*HD_*L_;

  bf16x8 onesf;
  #pragma unroll
  for (int j=0;j<8;j++) onesf[j] = (bf16_t)1.0f;

  floatx4 zero4 = {0.f,0.f,0.f,0.f};
  floatx4 accO[2][4];
  floatx4 accS[2];
  accS[0] = zero4; accS[1] = zero4;
  #pragma unroll
  for (int n=0;n<2;n++)
    #pragma unroll
    for (int dt=0;dt<4;dt++) accO[n][dt] = zero4;

  floatx4 StA[2][4], StB[2][4];

  auto stage = [&](int it, int c) {
    #pragma unroll
    for (int j=0;j<2;j++) {
      int row = wave*16 + j*8 + srow8;
      int col = ((sslot ^ (row&7)) << 3);
      async_copy16(Kg + (size_t)(it*64 + row)*D_ + col, &Ks[c][(wave*16 + j*8)*64]);
      async_copy16(Vg + (size_t)row*L_ + it*64 + col,   &Vs[c][(wave*16 + j*8)*64]);
    }
  };

  // prologue: tiles 0 and 1 landed (iter 0 needs QK^T of tile 1).
  stage(0, 0);
  stage(1, 1);
  asm volatile("s_waitcnt vmcnt(0)" ::: "memory");
  __builtin_amdgcn_s_barrier();

// QK^T of buffer CN into SN (all-static indices)
#define QKT_M(CN, SN)                                                         \
    _Pragma("unroll")                                                         \
    for (int t=0;t<4;t++) { SN[0][t]=zero4; SN[1][t]=zero4; }                 \
    _Pragma("unroll")                                                         \
    for (int t=0;t<4;t++) {                                                   \
      _Pragma("unroll")                                                       \
      for (int ks=0;ks<2;ks++) {                                              \
        bf16x8 kf = *(const bf16x8*)&Ks[CN][(t*16+slr)*64 + (((ks*4+quad) ^ (slr&7))<<3)]; \
        SN[0][t] = __builtin_amdgcn_mfma_f32_16x16x32_bf16(kf, qf[0][ks], SN[0][t], 0,0,0); \
        SN[1][t] = __builtin_amdgcn_mfma_f32_16x16x32_bf16(kf, qf[1][ks], SN[1][t], 0,0,0); \
      }                                                                       \
    }

  QKT_M(0, StA)   // tile 0

// Pipelined body: softmax(SC) || QK^T(buf (CC+1)%3 -> SN) || PV(buf CC).
#define ATTN_BODY(IT, CC, SC, SN, DO_STAGE, DO_QKT, DO_SYNC)                  \
  {                                                                           \
    if (DO_STAGE) stage((IT)+2, ((CC)+2)%3);                                  \
    bf16x8 pfv[2][2];                                                         \
    _Pragma("unroll")                                                         \
    for (int n=0;n<2;n++) {                                                   \
      _Pragma("unroll")                                                       \
      for (int hh=0;hh<2;hh++) {                                              \
        unsigned int w00 = cvt_pk(exp2f(SC[n][2*hh][0]),   exp2f(SC[n][2*hh][1]));   \
        unsigned int w01 = cvt_pk(exp2f(SC[n][2*hh][2]),   exp2f(SC[n][2*hh][3]));   \
        unsigned int w10 = cvt_pk(exp2f(SC[n][2*hh+1][0]), exp2f(SC[n][2*hh+1][1])); \
        unsigned int w11 = cvt_pk(exp2f(SC[n][2*hh+1][2]), exp2f(SC[n][2*hh+1][3])); \
        u32x2 r0 = __builtin_amdgcn_permlane32_swap(w00, w10, false, false);  \
        u32x2 r1 = __builtin_amdgcn_permlane32_swap(w01, w11, false, false);  \
        union { unsigned int u[4]; bf16x8 v; } pu;                            \
        pu.u[0] = r0.x; pu.u[1] = r1.x; pu.u[2] = r0.y; pu.u[3] = r1.y;       \
        pfv[n][hh] = pu.v;                                                    \
      }                                                                       \
    }                                                                         \
    if (DO_QKT) { QKT_M(((CC)+1)%3, SN) }                                     \
    _Pragma("unroll")                                                         \
    for (int dt=0;dt<4;dt++) {                                                \
      _Pragma("unroll")                                                       \
      for (int hh=0;hh<2;hh++) {                                              \
        bf16x8 vf = *(const bf16x8*)&Vs[CC][(dt*16+lr)*64 + (((hh*4+quad) ^ (lr&7))<<3)]; \
        accO[0][dt] = __builtin_amdgcn_mfma_f32_16x16x32_bf16(vf, pfv[0][hh], accO[0][dt], 0,0,0); \
        accO[1][dt] = __builtin_amdgcn_mfma_f32_16x16x32_bf16(vf, pfv[1][hh], accO[1][dt], 0,0,0); \
      }                                                                       \
    }                                                                         \
    accS[0] = __builtin_amdgcn_mfma_f32_16x16x32_bf16(onesf, pfv[0][0], accS[0], 0,0,0); \
    accS[1] = __builtin_amdgcn_mfma_f32_16x16x32_bf16(onesf, pfv[1][0], accS[1], 0,0,0); \
    accS[0] = __builtin_amdgcn_mfma_f32_16x16x32_bf16(onesf, pfv[0][1], accS[0], 0,0,0); \
    accS[1] = __builtin_amdgcn_mfma_f32_16x16x32_bf16(onesf, pfv[1][1], accS[1], 0,0,0); \
    if (DO_SYNC) {                                                            \
      asm volatile("s_waitcnt vmcnt(0)" ::: "memory");                        \
      __builtin_amdgcn_s_barrier();                                           \
    }                                                                         \
  }

  #pragma unroll 1
  for (int itb = 0; itb < 30; itb += 6) {
    ATTN_BODY(itb+0, 0, StA, StB, true, true, true);
    ATTN_BODY(itb+1, 1, StB, StA, true, true, true);
    ATTN_BODY(itb+2, 2, StA, StB, true, true, true);
    ATTN_BODY(itb+3, 0, StB, StA, true, true, true);
    ATTN_BODY(itb+4, 1, StA, StB, true, true, true);
    ATTN_BODY(itb+5, 2, StB, StA, true, true, true);
  }
  ATTN_BODY(30, 0, StA, StB, false, true,  false);
  ATTN_BODY(31, 1, StB, StA, false, false, false);
#undef ATTN_BODY
#undef QKT_M

  float inv0 = 1.0f / accS[0][0];
  float inv1 = 1.0f / accS[1][0];
  #pragma unroll
  for (int n=0;n<2;n++) {
    float inv = n ? inv1 : inv0;
    #pragma unroll
    for (int dt=0;dt<4;dt++) {
      uint2 w;
      w.x = cvt_pk(accO[n][dt][0]*inv, accO[n][dt][1]*inv);
      w.y = cvt_pk(accO[n][dt][2]*inv, accO[n][dt][3]*inv);
      *(uint2*)&O[(rowQ + n*16 + lr)*D_ + h*HD_ + dt*16 + quad*4] = w;
    }
  }
}

// ------------------------------ launch -------------------------------------
extern "C" void kernel_launch(void* const* d_in, const int* in_sizes, int n_in,
                              void* d_out, int out_size, void* d_ws, size_t ws_size,
                              hipStream_t stream) {
  const float* x  = (const float*)d_in[0];
  const float* wq = (const float*)d_in[1];
  const float* wk = (const float*)d_in[2];
  const float* wv = (const float*)d_in[3];
  const float* wo = (const float*)d_in[4];

  char* ws = (char*)d_ws;
  bf16_t* xb  = (bf16_t*)(ws);                       // 16MB; reused as O after attn
  bf16_t* Qb  = (bf16_t*)(ws + (size_t)(16u<<20));
  bf16_t* Kb  = (bf16_t*)(ws + (size_t)(32u<<20));
  bf16_t* Vtb = (bf16_t*)(ws + (size_t)(48u<<20));
  bf16_t* wqb = (bf16_t*)(ws + (size_t)(64u<<20));
  bf16_t* wkb = (bf16_t*)(ws + (size_t)(66u<<20));
  bf16_t* wvb = (bf16_t*)(ws + (size_t)(68u<<20));
  bf16_t* wob = (bf16_t*)(ws + (size_t)(70u<<20));
  float* cosT = (float*)(ws + (size_t)(72u<<20));
  float* sinT = (float*)(ws + (size_t)(72u<<20) + (256u<<10));
  bf16_t* Ob = xb;

  prep_kernel<<<6400, 256, 0, stream>>>(x, wq, wk, wv, wo, xb, wqb, wkb, wvb, wob, cosT, sinT);
  gemm_kernel<0><<<dim3(64,8,3), 256, 0, stream>>>(xb, wqb, wkb, wvb, Qb, Kb, Vtb, nullptr, cosT, sinT);
  attn_kernel<<<dim3(64,16), 256, 0, stream>>>(Qb, Kb, Vtb, Ob);
  gemm_kernel<1><<<dim3(64,8,1), 256, 0, stream>>>(Ob, wob, nullptr, nullptr,
                                                   nullptr, nullptr, nullptr, (float*)d_out, cosT, sinT);
}